// Round 4
// baseline (323.123 us; speedup 1.0000x reference)
//
#include <hip/hip_runtime.h>
#include <hip/hip_bf16.h>

typedef __bf16 bf16_t;
typedef __attribute__((ext_vector_type(8))) __bf16 bf16x8;
typedef __attribute__((ext_vector_type(4))) float f32x4;

#define NTOK 4096
#define DIM  768
#define NH   12
#define HD   64

static_assert(sizeof(bf16x8) == 16, "bf16x8 must be 16B");

__device__ __forceinline__ bf16x8 load8(const bf16_t* p) {
    return *reinterpret_cast<const bf16x8*>(p);
}
__device__ __forceinline__ void store8(bf16_t* p, bf16x8 v) {
    *reinterpret_cast<bf16x8*>(p) = v;
}
// load 8 contiguous fp32, round to bf16x8
__device__ __forceinline__ bf16x8 cvt8(const float* p) {
    float4 a = *reinterpret_cast<const float4*>(p);
    float4 b = *reinterpret_cast<const float4*>(p + 4);
    bf16x8 r;
    r[0] = (bf16_t)a.x; r[1] = (bf16_t)a.y; r[2] = (bf16_t)a.z; r[3] = (bf16_t)a.w;
    r[4] = (bf16_t)b.x; r[5] = (bf16_t)b.y; r[6] = (bf16_t)b.z; r[7] = (bf16_t)b.w;
    return r;
}

// ---------------------------------------------------------------------------
// QKV GEMM: C[m,n] = sum_k X[m,k] * Wqkv[n,k]   (x @ w_qkv.T), fp32 in.
// Epilogue scatters n -> (t, h, d):
//   t=0: Q[h][m][d]   t=1: K[h][m][d]   t=2: Vt[h][d][m]  (V transposed)
// ---------------------------------------------------------------------------
__global__ __launch_bounds__(256) void qkv_gemm_kernel(
    const float* __restrict__ X, const float* __restrict__ W,
    bf16_t* __restrict__ Qo, bf16_t* __restrict__ Ko, bf16_t* __restrict__ Vt)
{
    __shared__ __align__(16) bf16_t As[64 * 40];   // rows padded 32->40
    __shared__ __align__(16) bf16_t Bs[64 * 40];
    const int tid  = threadIdx.x;
    const int wave = tid >> 6, lane = tid & 63;
    const int lr = lane & 15, lq = lane >> 4;
    const int M0 = blockIdx.x * 64;
    const int N0 = blockIdx.y * 64;
    const int srow = tid >> 2, scol = (tid & 3) * 8;
    const int wr = (wave >> 1) * 32, wc = (wave & 1) * 32;

    f32x4 acc[2][2] = {};

    for (int k0 = 0; k0 < DIM; k0 += 32) {
        store8(&As[srow * 40 + scol], cvt8(&X[(size_t)(M0 + srow) * DIM + k0 + scol]));
        store8(&Bs[srow * 40 + scol], cvt8(&W[(size_t)(N0 + srow) * DIM + k0 + scol]));
        __syncthreads();
        bf16x8 a0 = load8(&As[(wr + lr) * 40 + lq * 8]);
        bf16x8 a1 = load8(&As[(wr + 16 + lr) * 40 + lq * 8]);
        bf16x8 b0 = load8(&Bs[(wc + lr) * 40 + lq * 8]);
        bf16x8 b1 = load8(&Bs[(wc + 16 + lr) * 40 + lq * 8]);
        acc[0][0] = __builtin_amdgcn_mfma_f32_16x16x32_bf16(a0, b0, acc[0][0], 0, 0, 0);
        acc[0][1] = __builtin_amdgcn_mfma_f32_16x16x32_bf16(a0, b1, acc[0][1], 0, 0, 0);
        acc[1][0] = __builtin_amdgcn_mfma_f32_16x16x32_bf16(a1, b0, acc[1][0], 0, 0, 0);
        acc[1][1] = __builtin_amdgcn_mfma_f32_16x16x32_bf16(a1, b1, acc[1][1], 0, 0, 0);
        __syncthreads();
    }

    const int t = N0 / DIM;
    const int h = (N0 % DIM) / HD;
    for (int r = 0; r < 2; ++r)
        for (int c = 0; c < 2; ++c)
            for (int reg = 0; reg < 4; ++reg) {
                int m = M0 + wr + r * 16 + lq * 4 + reg;   // C/D row = quad*4+reg
                int d = wc + c * 16 + lr;                  // C/D col = lane&15
                bf16_t v = (bf16_t)acc[r][c][reg];
                if (t == 0)      Qo[(h * NTOK + m) * HD + d] = v;
                else if (t == 1) Ko[(h * NTOK + m) * HD + d] = v;
                else             Vt[(h * HD + d) * NTOK + m] = v;
            }
}

// ---------------------------------------------------------------------------
// Flash attention: one block = (head h, 64 Q-rows). 4 waves x 16 Q-rows.
// ---------------------------------------------------------------------------
__global__ __launch_bounds__(256) void flash_attn_kernel(
    const bf16_t* __restrict__ Qb, const bf16_t* __restrict__ Kb,
    const bf16_t* __restrict__ Vtb, bf16_t* __restrict__ AO)
{
    __shared__ __align__(16) bf16_t Ks[64 * 72];   // [key][d], padded
    __shared__ __align__(16) bf16_t Vs[64 * 72];   // [d][key]
    __shared__ __align__(16) bf16_t Ps[4][16 * 72];// per-wave P: [qrow][key]
    const int tid  = threadIdx.x;
    const int wave = tid >> 6, lane = tid & 63;
    const int lr = lane & 15, lq = lane >> 4;
    const int h  = blockIdx.y;
    const int q0 = blockIdx.x * 64;

    const bf16_t* qrow = &Qb[((size_t)h * NTOK + q0 + wave * 16 + lr) * HD];
    bf16x8 qf0 = load8(&qrow[lq * 8]);
    bf16x8 qf1 = load8(&qrow[32 + lq * 8]);

    float m_i[4], l_i[4];
    f32x4 oacc[4] = {};
    for (int r = 0; r < 4; ++r) { m_i[r] = -1e30f; l_i[r] = 0.f; }

    const float scale = 0.125f;   // 1/sqrt(64)

    for (int kt = 0; kt < NTOK; kt += 64) {
        for (int rnd = 0; rnd < 2; ++rnd) {
            int pos = (rnd * 256 + tid) * 8;
            int row = pos >> 6, col = pos & 63;
            store8(&Ks[row * 72 + col], load8(&Kb[((size_t)h * NTOK + kt + row) * HD + col]));
            store8(&Vs[row * 72 + col], load8(&Vtb[((size_t)h * HD + row) * NTOK + kt + col]));
        }
        __syncthreads();

        f32x4 s[4];
        for (int g = 0; g < 4; ++g) {
            f32x4 z = {};
            bf16x8 b0 = load8(&Ks[(g * 16 + lr) * 72 + lq * 8]);
            bf16x8 b1 = load8(&Ks[(g * 16 + lr) * 72 + 32 + lq * 8]);
            z = __builtin_amdgcn_mfma_f32_16x16x32_bf16(qf0, b0, z, 0, 0, 0);
            z = __builtin_amdgcn_mfma_f32_16x16x32_bf16(qf1, b1, z, 0, 0, 0);
            for (int r = 0; r < 4; ++r) s[g][r] = z[r] * scale;
        }

        float mt[4];
        for (int r = 0; r < 4; ++r)
            mt[r] = fmaxf(fmaxf(s[0][r], s[1][r]), fmaxf(s[2][r], s[3][r]));
        for (int off = 1; off < 16; off <<= 1)
            for (int r = 0; r < 4; ++r)
                mt[r] = fmaxf(mt[r], __shfl_xor(mt[r], off, 64));

        float alpha[4], ls[4];
        float p[4][4];
        for (int r = 0; r < 4; ++r) {
            float mn = fmaxf(m_i[r], mt[r]);
            alpha[r] = __expf(m_i[r] - mn);
            m_i[r] = mn;
            ls[r] = 0.f;
        }
        for (int g = 0; g < 4; ++g)
            for (int r = 0; r < 4; ++r) {
                p[g][r] = __expf(s[g][r] - m_i[r]);
                ls[r] += p[g][r];
            }
        for (int off = 1; off < 16; off <<= 1)
            for (int r = 0; r < 4; ++r)
                ls[r] += __shfl_xor(ls[r], off, 64);
        for (int r = 0; r < 4; ++r) l_i[r] = l_i[r] * alpha[r] + ls[r];
        for (int g = 0; g < 4; ++g)
            for (int r = 0; r < 4; ++r) oacc[g][r] *= alpha[r];

        for (int g = 0; g < 4; ++g)
            for (int r = 0; r < 4; ++r)
                Ps[wave][(lq * 4 + r) * 72 + g * 16 + lr] = (bf16_t)p[g][r];
        __syncthreads();

        bf16x8 pa0 = load8(&Ps[wave][lr * 72 + lq * 8]);
        bf16x8 pa1 = load8(&Ps[wave][lr * 72 + 32 + lq * 8]);
        for (int g = 0; g < 4; ++g) {
            bf16x8 v0 = load8(&Vs[(g * 16 + lr) * 72 + lq * 8]);
            bf16x8 v1 = load8(&Vs[(g * 16 + lr) * 72 + 32 + lq * 8]);
            oacc[g] = __builtin_amdgcn_mfma_f32_16x16x32_bf16(pa0, v0, oacc[g], 0, 0, 0);
            oacc[g] = __builtin_amdgcn_mfma_f32_16x16x32_bf16(pa1, v1, oacc[g], 0, 0, 0);
        }
        __syncthreads();
    }

    for (int g = 0; g < 4; ++g)
        for (int r = 0; r < 4; ++r) {
            int m = q0 + wave * 16 + lq * 4 + r;
            int d = g * 16 + lr;
            AO[(size_t)m * DIM + h * HD + d] = (bf16_t)(oacc[g][r] / l_i[r]);
        }
}

// ---------------------------------------------------------------------------
// Proj GEMM: out[m,n] = sum_k AO[m,k] * Wp[n,k] + bias[n]   -> FP32 out
// ---------------------------------------------------------------------------
__global__ __launch_bounds__(256) void proj_gemm_kernel(
    const bf16_t* __restrict__ A, const float* __restrict__ W,
    const float* __restrict__ bias, float* __restrict__ out)
{
    __shared__ __align__(16) bf16_t As[64 * 40];
    __shared__ __align__(16) bf16_t Bs[64 * 40];
    const int tid  = threadIdx.x;
    const int wave = tid >> 6, lane = tid & 63;
    const int lr = lane & 15, lq = lane >> 4;
    const int M0 = blockIdx.x * 64;
    const int N0 = blockIdx.y * 64;
    const int srow = tid >> 2, scol = (tid & 3) * 8;
    const int wr = (wave >> 1) * 32, wc = (wave & 1) * 32;

    f32x4 acc[2][2] = {};

    for (int k0 = 0; k0 < DIM; k0 += 32) {
        store8(&As[srow * 40 + scol], load8(&A[(size_t)(M0 + srow) * DIM + k0 + scol]));
        store8(&Bs[srow * 40 + scol], cvt8(&W[(size_t)(N0 + srow) * DIM + k0 + scol]));
        __syncthreads();
        bf16x8 a0 = load8(&As[(wr + lr) * 40 + lq * 8]);
        bf16x8 a1 = load8(&As[(wr + 16 + lr) * 40 + lq * 8]);
        bf16x8 b0 = load8(&Bs[(wc + lr) * 40 + lq * 8]);
        bf16x8 b1 = load8(&Bs[(wc + 16 + lr) * 40 + lq * 8]);
        acc[0][0] = __builtin_amdgcn_mfma_f32_16x16x32_bf16(a0, b0, acc[0][0], 0, 0, 0);
        acc[0][1] = __builtin_amdgcn_mfma_f32_16x16x32_bf16(a0, b1, acc[0][1], 0, 0, 0);
        acc[1][0] = __builtin_amdgcn_mfma_f32_16x16x32_bf16(a1, b0, acc[1][0], 0, 0, 0);
        acc[1][1] = __builtin_amdgcn_mfma_f32_16x16x32_bf16(a1, b1, acc[1][1], 0, 0, 0);
        __syncthreads();
    }

    for (int r = 0; r < 2; ++r)
        for (int c = 0; c < 2; ++c)
            for (int reg = 0; reg < 4; ++reg) {
                int m = M0 + wr + r * 16 + lq * 4 + reg;
                int n = N0 + wc + c * 16 + lr;
                out[(size_t)m * DIM + n] = acc[r][c][reg] + bias[n];   // fp32 out
            }
}

// ---------------------------------------------------------------------------
extern "C" void kernel_launch(void* const* d_in, const int* in_sizes, int n_in,
                              void* d_out, int out_size, void* d_ws, size_t ws_size,
                              hipStream_t stream)
{
    const float* x      = (const float*)d_in[0];
    const float* w_qkv  = (const float*)d_in[1];
    const float* w_proj = (const float*)d_in[2];
    const float* b_proj = (const float*)d_in[3];
    float* out = (float*)d_out;   // reference output dtype is fp32

    char* ws = (char*)d_ws;
    const size_t sz = (size_t)NH * NTOK * HD * sizeof(bf16_t);  // 6,291,456 B
    bf16_t* Q  = (bf16_t*)(ws);
    bf16_t* K  = (bf16_t*)(ws + sz);
    bf16_t* Vt = (bf16_t*)(ws + 2 * sz);
    bf16_t* AO = (bf16_t*)(ws + 3 * sz);   // ~25 MB workspace

    qkv_gemm_kernel<<<dim3(NTOK / 64, (3 * DIM) / 64), 256, 0, stream>>>(x, w_qkv, Q, K, Vt);
    flash_attn_kernel<<<dim3(NTOK / 64, NH), 256, 0, stream>>>(Q, K, Vt, AO);
    proj_gemm_kernel<<<dim3(NTOK / 64, DIM / 64), 256, 0, stream>>>(AO, w_proj, b_proj, out);
}

// Round 5
// 249.228 us; speedup vs baseline: 1.2965x; 1.2965x over previous
//
#include <hip/hip_runtime.h>
#include <hip/hip_bf16.h>

typedef __bf16 bf16_t;
typedef __attribute__((ext_vector_type(8))) __bf16 bf16x8;
typedef __attribute__((ext_vector_type(4))) __bf16 bf16x4;
typedef __attribute__((ext_vector_type(4))) short s16x4;
typedef __attribute__((ext_vector_type(4))) float f32x4;

#define NTOK 4096
#define DIM  768
#define NH   12
#define HD   64
#define XSZ  (NTOK * DIM)       // 3,145,728
#define WQSZ (3 * DIM * DIM)    // 1,769,472
#define WPSZ (DIM * DIM)        //   589,824
// 0.125 * log2(e): folded into Q so S^T is directly in log2 domain
#define SCALE_L2E 0.18033688011112042f

__device__ __forceinline__ bf16x8 load8(const bf16_t* p) {
    return *reinterpret_cast<const bf16x8*>(p);
}
__device__ __forceinline__ void store8(bf16_t* p, bf16x8 v) {
    *reinterpret_cast<bf16x8*>(p) = v;
}

// ---------------------------------------------------------------------------
// Convert fp32 inputs to bf16 once (memory-bound, ~33 MB total).
// ---------------------------------------------------------------------------
__global__ __launch_bounds__(256) void cvt_kernel(
    const float* __restrict__ x, const float* __restrict__ wq,
    const float* __restrict__ wp,
    bf16_t* __restrict__ xb, bf16_t* __restrict__ wqb, bf16_t* __restrict__ wpb)
{
    size_t i = ((size_t)blockIdx.x * 256 + threadIdx.x) * 4;
    const float* src; bf16_t* dst; size_t off;
    if (i < XSZ)             { src = x;  dst = xb;  off = i; }
    else if (i < XSZ + WQSZ) { src = wq; dst = wqb; off = i - XSZ; }
    else                     { src = wp; dst = wpb; off = i - XSZ - WQSZ; }
    float4 v = *reinterpret_cast<const float4*>(src + off);
    bf16x4 o = { (bf16_t)v.x, (bf16_t)v.y, (bf16_t)v.z, (bf16_t)v.w };
    *reinterpret_cast<bf16x4*>(dst + off) = o;
}

// ---------------------------------------------------------------------------
// QKV GEMM (bf16 in): C[m,n] = sum_k X[m,k] * Wqkv[n,k], 128x128 tile, BK=32.
// 4 waves in 2x2; each wave 64x64 (4x4 MFMA 16x16x32).
// Epilogue scatter: t=0: Q[h][m][d] (*SCALE_L2E)  t=1: K[h][m][d]
//                   t=2: Vt[h][d][m]
// ---------------------------------------------------------------------------
__global__ __launch_bounds__(256) void qkv_gemm_kernel(
    const bf16_t* __restrict__ X, const bf16_t* __restrict__ W,
    bf16_t* __restrict__ Qo, bf16_t* __restrict__ Ko, bf16_t* __restrict__ Vt)
{
    __shared__ __align__(16) bf16_t As[128 * 40];   // rows padded 32->40
    __shared__ __align__(16) bf16_t Bs[128 * 40];
    const int tid  = threadIdx.x;
    const int wave = tid >> 6, lane = tid & 63;
    const int lr = lane & 15, lq = lane >> 4;
    const int M0 = blockIdx.x * 128;
    const int N0 = blockIdx.y * 128;
    const int srow = tid >> 1, scol = (tid & 1) * 16;   // 128 rows x 32 cols
    const int wm = (wave >> 1) * 64, wn = (wave & 1) * 64;

    f32x4 acc[4][4] = {};

    for (int k0 = 0; k0 < DIM; k0 += 32) {
        store8(&As[srow * 40 + scol],     load8(&X[(size_t)(M0 + srow) * DIM + k0 + scol]));
        store8(&As[srow * 40 + scol + 8], load8(&X[(size_t)(M0 + srow) * DIM + k0 + scol + 8]));
        store8(&Bs[srow * 40 + scol],     load8(&W[(size_t)(N0 + srow) * DIM + k0 + scol]));
        store8(&Bs[srow * 40 + scol + 8], load8(&W[(size_t)(N0 + srow) * DIM + k0 + scol + 8]));
        __syncthreads();
        bf16x8 af[4], bfr[4];
        #pragma unroll
        for (int i = 0; i < 4; ++i) af[i]  = load8(&As[(wm + i * 16 + lr) * 40 + lq * 8]);
        #pragma unroll
        for (int i = 0; i < 4; ++i) bfr[i] = load8(&Bs[(wn + i * 16 + lr) * 40 + lq * 8]);
        #pragma unroll
        for (int r = 0; r < 4; ++r)
            #pragma unroll
            for (int c = 0; c < 4; ++c)
                acc[r][c] = __builtin_amdgcn_mfma_f32_16x16x32_bf16(af[r], bfr[c], acc[r][c], 0, 0, 0);
        __syncthreads();
    }

    const int t = N0 / DIM;      // uniform per block (768 % 128 == 0)
    #pragma unroll
    for (int r = 0; r < 4; ++r)
        #pragma unroll
        for (int c = 0; c < 4; ++c)
            #pragma unroll
            for (int reg = 0; reg < 4; ++reg) {
                int m = M0 + wm + r * 16 + lq * 4 + reg;
                int n = N0 + wn + c * 16 + lr;
                int rem = n - t * DIM;
                int h = rem >> 6, d = rem & 63;
                float v = acc[r][c][reg];
                if (t == 0)      Qo[(h * NTOK + m) * HD + d] = (bf16_t)(v * SCALE_L2E);
                else if (t == 1) Ko[(h * NTOK + m) * HD + d] = (bf16_t)v;
                else             Vt[(h * HD + d) * NTOK + m] = (bf16_t)v;
            }
}

// ---------------------------------------------------------------------------
// Flash attention, S^T formulation. Block = (64 q-rows, head); 4 waves x 16 q.
// S^T[key][q] = K·Q^T (log2 domain; Q pre-scaled). C/D layout puts all 16
// p-values of a lane on ONE q (=lane&15), keys = quad*4+reg — which IS the
// B-operand layout of mfma_16x16x16_bf16. P never touches LDS.
// O^T[d][q] += V^T·P via 16 K=16 MFMAs. 2 barriers/tile.
// ---------------------------------------------------------------------------
__global__ __launch_bounds__(256) void flash_attn_kernel(
    const bf16_t* __restrict__ Qb, const bf16_t* __restrict__ Kb,
    const bf16_t* __restrict__ Vtb, bf16_t* __restrict__ AO)
{
    __shared__ __align__(16) bf16_t Ks[64 * 72];   // [key][d], padded
    __shared__ __align__(16) bf16_t Vs[64 * 72];   // [d][key]
    const int tid  = threadIdx.x;
    const int wave = tid >> 6, lane = tid & 63;
    const int lr = lane & 15, lq = lane >> 4;
    const int h  = blockIdx.y;
    const int q0 = blockIdx.x * 64;

    // Q as B-operand of S^T: lane n=lr -> q row, k=d=lq*8+j
    const bf16_t* qrow = &Qb[((size_t)h * NTOK + q0 + wave * 16 + lr) * HD];
    bf16x8 qf0 = load8(&qrow[lq * 8]);
    bf16x8 qf1 = load8(&qrow[32 + lq * 8]);

    float m_i = -1e30f, l_i = 0.f;     // per-lane scalars: this lane's q = lr
    f32x4 oacc[4] = {};                // oacc[dt]: O^T[dt*16+lq*4+reg][lr]

    for (int kt = 0; kt < NTOK; kt += 64) {
        #pragma unroll
        for (int rnd = 0; rnd < 2; ++rnd) {
            int pos = (rnd * 256 + tid) * 8;
            int row = pos >> 6, col = pos & 63;
            store8(&Ks[row * 72 + col], load8(&Kb[((size_t)h * NTOK + kt + row) * HD + col]));
            store8(&Vs[row * 72 + col], load8(&Vtb[((size_t)h * HD + row) * NTOK + kt + col]));
        }
        __syncthreads();

        // S^T: 4 key-subtiles of 16, A = K rows, B = Q rows
        f32x4 st[4];
        #pragma unroll
        for (int g = 0; g < 4; ++g) {
            f32x4 z = {};
            bf16x8 k0 = load8(&Ks[(g * 16 + lr) * 72 + lq * 8]);
            bf16x8 k1 = load8(&Ks[(g * 16 + lr) * 72 + 32 + lq * 8]);
            z = __builtin_amdgcn_mfma_f32_16x16x32_bf16(k0, qf0, z, 0, 0, 0);
            z = __builtin_amdgcn_mfma_f32_16x16x32_bf16(k1, qf1, z, 0, 0, 0);
            st[g] = z;
        }

        // row stats for q=lr: 16 in-lane keys, then across 4 quads
        float mt = -1e30f;
        #pragma unroll
        for (int g = 0; g < 4; ++g)
            #pragma unroll
            for (int r = 0; r < 4; ++r) mt = fmaxf(mt, st[g][r]);
        mt = fmaxf(mt, __shfl_xor(mt, 16));
        mt = fmaxf(mt, __shfl_xor(mt, 32));

        float mnew  = fmaxf(m_i, mt);
        float alpha = __builtin_amdgcn_exp2f(m_i - mnew);
        float ls = 0.f;
        #pragma unroll
        for (int g = 0; g < 4; ++g)
            #pragma unroll
            for (int r = 0; r < 4; ++r) {
                st[g][r] = __builtin_amdgcn_exp2f(st[g][r] - mnew);
                ls += st[g][r];
            }
        ls += __shfl_xor(ls, 16);
        ls += __shfl_xor(ls, 32);
        l_i = l_i * alpha + ls;
        m_i = mnew;
        #pragma unroll
        for (int dt = 0; dt < 4; ++dt)
            #pragma unroll
            for (int r = 0; r < 4; ++r) oacc[dt][r] *= alpha;

        // PV: O^T[d][q] += sum over key-chunks g; B = P straight from regs
        #pragma unroll
        for (int g = 0; g < 4; ++g) {
            bf16x4 pb = { (bf16_t)st[g][0], (bf16_t)st[g][1],
                          (bf16_t)st[g][2], (bf16_t)st[g][3] };
            s16x4 ps = __builtin_bit_cast(s16x4, pb);
            #pragma unroll
            for (int dt = 0; dt < 4; ++dt) {
                s16x4 va = *reinterpret_cast<const s16x4*>(
                    &Vs[(dt * 16 + lr) * 72 + g * 16 + lq * 4]);
                oacc[dt] = __builtin_amdgcn_mfma_f32_16x16x16bf16_1k(va, ps, oacc[dt], 0, 0, 0);
            }
        }
        __syncthreads();   // all waves done with Ks/Vs before next staging
    }

    // epilogue: O^T -> AO[m][h*64+d], divide by l (per-lane scalar)
    const int m = q0 + wave * 16 + lr;
    float rinv = 1.f / l_i;
    #pragma unroll
    for (int dt = 0; dt < 4; ++dt)
        #pragma unroll
        for (int r = 0; r < 4; ++r) {
            int d = dt * 16 + lq * 4 + r;
            AO[(size_t)m * DIM + h * HD + d] = (bf16_t)(oacc[dt][r] * rinv);
        }
}

// ---------------------------------------------------------------------------
// Proj GEMM: out[m,n] = sum_k AO[m,k] * Wp[n,k] + bias[n]  -> fp32 out.
// 64x64 tile (validated structure), bf16 W.
// ---------------------------------------------------------------------------
__global__ __launch_bounds__(256) void proj_gemm_kernel(
    const bf16_t* __restrict__ A, const bf16_t* __restrict__ W,
    const float* __restrict__ bias, float* __restrict__ out)
{
    __shared__ __align__(16) bf16_t As[64 * 40];
    __shared__ __align__(16) bf16_t Bs[64 * 40];
    const int tid  = threadIdx.x;
    const int wave = tid >> 6, lane = tid & 63;
    const int lr = lane & 15, lq = lane >> 4;
    const int M0 = blockIdx.x * 64;
    const int N0 = blockIdx.y * 64;
    const int srow = tid >> 2, scol = (tid & 3) * 8;
    const int wr = (wave >> 1) * 32, wc = (wave & 1) * 32;

    f32x4 acc[2][2] = {};

    for (int k0 = 0; k0 < DIM; k0 += 32) {
        store8(&As[srow * 40 + scol], load8(&A[(size_t)(M0 + srow) * DIM + k0 + scol]));
        store8(&Bs[srow * 40 + scol], load8(&W[(size_t)(N0 + srow) * DIM + k0 + scol]));
        __syncthreads();
        bf16x8 a0 = load8(&As[(wr + lr) * 40 + lq * 8]);
        bf16x8 a1 = load8(&As[(wr + 16 + lr) * 40 + lq * 8]);
        bf16x8 b0 = load8(&Bs[(wc + lr) * 40 + lq * 8]);
        bf16x8 b1 = load8(&Bs[(wc + 16 + lr) * 40 + lq * 8]);
        acc[0][0] = __builtin_amdgcn_mfma_f32_16x16x32_bf16(a0, b0, acc[0][0], 0, 0, 0);
        acc[0][1] = __builtin_amdgcn_mfma_f32_16x16x32_bf16(a0, b1, acc[0][1], 0, 0, 0);
        acc[1][0] = __builtin_amdgcn_mfma_f32_16x16x32_bf16(a1, b0, acc[1][0], 0, 0, 0);
        acc[1][1] = __builtin_amdgcn_mfma_f32_16x16x32_bf16(a1, b1, acc[1][1], 0, 0, 0);
        __syncthreads();
    }

    #pragma unroll
    for (int r = 0; r < 2; ++r)
        #pragma unroll
        for (int c = 0; c < 2; ++c)
            #pragma unroll
            for (int reg = 0; reg < 4; ++reg) {
                int m = M0 + wr + r * 16 + lq * 4 + reg;
                int n = N0 + wc + c * 16 + lr;
                out[(size_t)m * DIM + n] = acc[r][c][reg] + bias[n];
            }
}

// ---------------------------------------------------------------------------
extern "C" void kernel_launch(void* const* d_in, const int* in_sizes, int n_in,
                              void* d_out, int out_size, void* d_ws, size_t ws_size,
                              hipStream_t stream)
{
    const float* x      = (const float*)d_in[0];
    const float* w_qkv  = (const float*)d_in[1];
    const float* w_proj = (const float*)d_in[2];
    const float* b_proj = (const float*)d_in[3];
    float* out = (float*)d_out;

    char* ws = (char*)d_ws;
    const size_t sz = (size_t)NH * NTOK * HD * sizeof(bf16_t);  // 6,291,456 B
    bf16_t* Q   = (bf16_t*)(ws);
    bf16_t* K   = (bf16_t*)(ws + sz);
    bf16_t* Vt  = (bf16_t*)(ws + 2 * sz);
    bf16_t* AO  = (bf16_t*)(ws + 3 * sz);
    bf16_t* xb  = (bf16_t*)(ws + 4 * sz);
    bf16_t* wqb = (bf16_t*)(ws + 4 * sz + (size_t)XSZ * 2);
    bf16_t* wpb = (bf16_t*)(ws + 4 * sz + (size_t)(XSZ + WQSZ) * 2);
    // total ~36.2 MB workspace

    cvt_kernel<<<dim3((XSZ + WQSZ + WPSZ) / 1024), 256, 0, stream>>>(
        x, w_qkv, w_proj, xb, wqb, wpb);
    qkv_gemm_kernel<<<dim3(NTOK / 128, (3 * DIM) / 128), 256, 0, stream>>>(
        xb, wqb, Q, K, Vt);
    flash_attn_kernel<<<dim3(NTOK / 64, NH), 256, 0, stream>>>(Q, K, Vt, AO);
    proj_gemm_kernel<<<dim3(NTOK / 64, DIM / 64), 256, 0, stream>>>(
        AO, wpb, b_proj, out);
}